// Round 3
// baseline (1584.764 us; speedup 1.0000x reference)
//
#include <hip/hip_runtime.h>
#include <hip/hip_bf16.h>
#include <stdint.h>

#define T_TOK 16384
#define HDIM  1024
#define IDIM  4096
#define NEXP  8

typedef __bf16  bf16x8  __attribute__((ext_vector_type(8)));
typedef float   floatx4 __attribute__((ext_vector_type(4)));

__device__ __forceinline__ void gload16(const void* g, void* lds) {
  __builtin_amdgcn_global_load_lds(
      (__attribute__((address_space(1))) void*)g,
      (__attribute__((address_space(3))) void*)lds, 16, 0, 0);
}

// ---------------- fp32 -> bf16 convert, 8 elems/thread ----------------
__global__ __launch_bounds__(256) void cvtk(const float* __restrict__ s,
                                            __bf16* __restrict__ d, int n8) {
  int i = blockIdx.x * 256 + threadIdx.x;
  if (i >= n8) return;
  const float4* s4 = (const float4*)s;
  float4 a = s4[2 * i], b = s4[2 * i + 1];
  bf16x8 v;
  v[0] = (__bf16)a.x; v[1] = (__bf16)a.y; v[2] = (__bf16)a.z; v[3] = (__bf16)a.w;
  v[4] = (__bf16)b.x; v[5] = (__bf16)b.y; v[6] = (__bf16)b.z; v[7] = (__bf16)b.w;
  *(bf16x8*)(d + (size_t)i * 8) = v;
}

// ---------------- router: fp32 logits, top-2, per-block LDS histogram ----------------
__global__ __launch_bounds__(256) void routerk(const float* __restrict__ x,
    const float* __restrict__ Wg, float* __restrict__ logits,
    int* __restrict__ topk_e, float* __restrict__ topk_g,
    int* __restrict__ gcount) {
  __shared__ int hist[NEXP];
  int tid = threadIdx.x;
  if (tid < NEXP) hist[tid] = 0;
  __syncthreads();
  int wv = tid >> 6, ln = tid & 63;
  for (int it = 0; it < 16; ++it) {
    int t = blockIdx.x * 64 + wv * 16 + it;
    const float* xr = x + (size_t)t * HDIM;
    float acc[NEXP];
#pragma unroll
    for (int e = 0; e < NEXP; e++) acc[e] = 0.f;
    for (int h = ln; h < HDIM; h += 64) {
      float xv = xr[h];
#pragma unroll
      for (int e = 0; e < NEXP; e++) acc[e] += xv * Wg[e * HDIM + h];
    }
#pragma unroll
    for (int e = 0; e < NEXP; e++) {
#pragma unroll
      for (int off = 32; off > 0; off >>= 1) acc[e] += __shfl_down(acc[e], off);
    }
    if (ln == 0) {
#pragma unroll
      for (int e = 0; e < NEXP; e++) logits[(size_t)t * NEXP + e] = acc[e];
      int i0 = 0;
#pragma unroll
      for (int e = 1; e < NEXP; e++) if (acc[e] > acc[i0]) i0 = e;
      int i1 = (i0 == 0) ? 1 : 0;
#pragma unroll
      for (int e = 0; e < NEXP; e++)
        if (e != i0 && e != i1 && acc[e] > acc[i1]) i1 = e;
      float r = expf(acc[i1] - acc[i0]);
      float s = 1.f + r;
      topk_e[2 * t] = i0;     topk_g[2 * t] = 1.f / s;
      topk_e[2 * t + 1] = i1; topk_g[2 * t + 1] = r / s;
      atomicAdd(&hist[i0], 1);
      atomicAdd(&hist[i1], 1);
    }
  }
  __syncthreads();
  if (tid < NEXP) atomicAdd(&gcount[tid], hist[tid]);
}

// ---------------- prefix + block tables (256-row blocks now) ----------------
__global__ void prefixk(const int* __restrict__ gcount, int* __restrict__ goff,
                        int* __restrict__ gcur, int* __restrict__ tbl,
                        int* __restrict__ ntb, int CH) {
  if (threadIdx.x != 0 || blockIdx.x != 0) return;
  int s = 0;
  for (int g = 0; g < NEXP; g++) { goff[g] = s; gcur[g] = s; s += gcount[g]; }
  goff[NEXP] = s;
  int chunk_rows = (2 * T_TOK) / CH;
  int cnt[16];
  for (int c = 0; c < CH; c++) cnt[c] = 0;
  for (int g = 0; g < NEXP; g++) {
    int Ne = goff[g + 1] - goff[g];
    int nb = (Ne + 255) >> 8;
    for (int b = 0; b < nb; b++) {
      int gr0 = goff[g] + b * 256;
      int c = gr0 / chunk_rows;
      tbl[c * 288 + cnt[c]] = (g << 8) | b;
      cnt[c]++;
    }
  }
  for (int c = 0; c < CH; c++) ntb[c] = cnt[c];
}

// ---------------- scatter: per-block LDS histogram + block-range reservation ----------------
__global__ __launch_bounds__(256) void scatterk(const int* __restrict__ topk_e,
    const float* __restrict__ topk_g, int* __restrict__ gcur,
    int* __restrict__ row_info, float* __restrict__ row_gate) {
  __shared__ int hist[NEXP];
  __shared__ int bbase[NEXP];
  int tid = threadIdx.x;
  if (tid < NEXP) hist[tid] = 0;
  __syncthreads();
  int t = blockIdx.x * 256 + tid;
  int e0 = topk_e[2 * t], e1 = topk_e[2 * t + 1];
  float g0 = topk_g[2 * t], g1 = topk_g[2 * t + 1];
  int l0 = atomicAdd(&hist[e0], 1);
  int l1 = atomicAdd(&hist[e1], 1);
  __syncthreads();
  if (tid < NEXP) bbase[tid] = atomicAdd(&gcur[tid], hist[tid]);
  __syncthreads();
  int p0 = bbase[e0] + l0;
  row_info[p0] = t; row_gate[p0] = g0;
  int p1 = bbase[e1] + l1;
  row_info[p1] = t; row_gate[p1] = g1;
}

// ============================================================================
// GEMM core: 256x256 tile, 8 waves (2M x 4N), BK=32, 16x16x32 bf16 MFMA.
//  - 4 LDS buffers x 32KB (A 16K + B 16K) = 128KB, prefetch distance 3 tiles.
//  - One counted s_waitcnt vmcnt(10) per tile (never 0 in steady state):
//    at tile t's wait, outstanding = t+1(4) + t+2(4) + A(t+3)(2) = 10 ops,
//    so tile t is guaranteed landed with ~3 tiles (~1200cy) latency cover.
//    Tail peels vmcnt(8)/(4)/(0). 2 raw s_barriers per tile.
//  - T2 swizzle: ds_read slot' = lq ^ ((row>>1)&3) -> each bank-quad hit
//    exactly 2x per quarter-wave (conflict-free). global_load_lds dest is
//    LINEAR; the global SOURCE column is pre-swizzled with the same
//    involution (rule #21): srccol16 = (tid&3) ^ ((tid>>3)&3).
//  - T5 setprio(1) around each 16-MFMA cluster.
// ============================================================================

// ---------------- GEMM1: hmid = silu(x @ W1[e]^T + b1[e]), bf16 out ----------------
__global__ __launch_bounds__(512, 2) void gemm1k(
    const __bf16* __restrict__ xb, const __bf16* __restrict__ w1b,
    const float* __restrict__ b1, __bf16* __restrict__ hmid,
    const int* __restrict__ row_info, const int* __restrict__ goff,
    const int* __restrict__ tbl, const int* __restrict__ ntb, int chunk_base) {
  __shared__ __attribute__((aligned(16))) char smem[131072];
  if ((int)blockIdx.x >= ntb[0]) return;
  int info = tbl[blockIdx.x];
  int g = info >> 8, br = info & 255;
  int base = goff[g];
  int Ne = goff[g + 1] - base;
  int r0 = br * 256;
  if (r0 >= Ne) return;
  int n0 = blockIdx.y * 256;
  int tid = threadIdx.x, wid = tid >> 6, ln = tid & 63;
  int wm = wid >> 2, wn = wid & 3;
  int lm = ln & 15, lq = ln >> 4;

  // staging: round r covers tile-rows r*128 + (tid>>2); source col pre-swizzled
  int rb = tid >> 2;
  int srcs = ((tid & 3) ^ ((tid >> 3) & 3)) * 16;
  const char* gA[2]; const char* gB[2];
#pragma unroll
  for (int r = 0; r < 2; r++) {
    int row = r0 + r * 128 + rb;
    int rc = row < Ne ? row : Ne - 1;
    int tk = row_info[base + rc];
    gA[r] = (const char*)(xb + (size_t)tk * HDIM) + srcs;
    gB[r] = (const char*)(w1b + (size_t)g * IDIM * HDIM +
                          (size_t)(n0 + r * 128 + rb) * HDIM) + srcs;
  }
  // frag read bases (swizzled)
  int swz = (lq ^ ((lm >> 1) & 3)) * 16;
  int rdA = (wm * 128 + lm) * 64 + swz;
  int rdB = 16384 + (wn * 64 + lm) * 64 + swz;

  floatx4 acc[8][4] = {};

#define STAGE_A1(T) { int b_ = (T) & 3; size_t ko = (size_t)(T) * 64; \
    gload16(gA[0] + ko, smem + b_ * 32768 + tid * 16); \
    gload16(gA[1] + ko, smem + b_ * 32768 + 8192 + tid * 16); }
#define STAGE_B1(T) { int b_ = (T) & 3; size_t ko = (size_t)(T) * 64; \
    gload16(gB[0] + ko, smem + b_ * 32768 + 16384 + tid * 16); \
    gload16(gB[1] + ko, smem + b_ * 32768 + 24576 + tid * 16); }

  const int NT = HDIM / 32;
  // prologue: tiles 0..2
#pragma unroll
  for (int p = 0; p < 3; p++) { STAGE_A1(p); STAGE_B1(p); }

#pragma unroll 1
  for (int t = 0; t < NT; t++) {
    bool st = (t < NT - 3);
    if (st) STAGE_A1(t + 3);
    int rem = NT - 1 - t;
    if (rem >= 3)      asm volatile("s_waitcnt vmcnt(10)" ::: "memory");
    else if (rem == 2) asm volatile("s_waitcnt vmcnt(8)" ::: "memory");
    else if (rem == 1) asm volatile("s_waitcnt vmcnt(4)" ::: "memory");
    else               asm volatile("s_waitcnt vmcnt(0)" ::: "memory");
    __builtin_amdgcn_s_barrier();
    asm volatile("" ::: "memory");
    const char* cb = smem + (t & 3) * 32768;
    bf16x8 af[8], bf[2];
#pragma unroll
    for (int mi = 0; mi < 8; mi++) af[mi] = *(const bf16x8*)(cb + rdA + mi * 1024);
#pragma unroll
    for (int ni = 0; ni < 2; ni++) bf[ni] = *(const bf16x8*)(cb + rdB + ni * 1024);
    __builtin_amdgcn_s_setprio(1);
#pragma unroll
    for (int mi = 0; mi < 8; mi++)
#pragma unroll
      for (int ni = 0; ni < 2; ni++)
        acc[mi][ni] = __builtin_amdgcn_mfma_f32_16x16x32_bf16(af[mi], bf[ni], acc[mi][ni], 0, 0, 0);
    __builtin_amdgcn_s_setprio(0);
    if (st) STAGE_B1(t + 3);
    bf16x8 bg[2];
#pragma unroll
    for (int ni = 0; ni < 2; ni++) bg[ni] = *(const bf16x8*)(cb + rdB + (2 + ni) * 1024);
    __builtin_amdgcn_s_setprio(1);
#pragma unroll
    for (int mi = 0; mi < 8; mi++)
#pragma unroll
      for (int ni = 0; ni < 2; ni++)
        acc[mi][2 + ni] = __builtin_amdgcn_mfma_f32_16x16x32_bf16(af[mi], bg[ni], acc[mi][2 + ni], 0, 0, 0);
    __builtin_amdgcn_s_setprio(0);
    asm volatile("" ::: "memory");
    __builtin_amdgcn_s_barrier();
    asm volatile("" ::: "memory");
  }
#undef STAGE_A1
#undef STAGE_B1

  int colbase = n0 + wn * 64;
#pragma unroll
  for (int mi = 0; mi < 8; mi++) {
#pragma unroll
    for (int reg = 0; reg < 4; reg++) {
      int rr = r0 + wm * 128 + mi * 16 + lq * 4 + reg;
      if (rr < Ne) {
        __bf16* orow = hmid + (size_t)(base + rr - chunk_base) * IDIM;
#pragma unroll
        for (int ni = 0; ni < 4; ni++) {
          int c = colbase + ni * 16 + lm;
          float v = acc[mi][ni][reg] + b1[g * IDIM + c];
          v = v / (1.f + __expf(-v));
          orow[c] = (__bf16)v;
        }
      }
    }
  }
}

// ---------------- GEMM2: out += gate * (hmid @ W2[e]^T + b2[e]) ----------------
__global__ __launch_bounds__(512, 2) void gemm2k(
    const __bf16* __restrict__ hmid, const __bf16* __restrict__ w2b,
    const float* __restrict__ b2, float* __restrict__ out,
    const int* __restrict__ row_info, const float* __restrict__ row_gate,
    const int* __restrict__ goff, const int* __restrict__ tbl,
    const int* __restrict__ ntb, int chunk_base) {
  __shared__ __attribute__((aligned(16))) char smem[131072];
  if ((int)blockIdx.x >= ntb[0]) return;
  int info = tbl[blockIdx.x];
  int g = info >> 8, br = info & 255;
  int base = goff[g];
  int Ne = goff[g + 1] - base;
  int r0 = br * 256;
  if (r0 >= Ne) return;
  int n0 = blockIdx.y * 256;
  int tid = threadIdx.x, wid = tid >> 6, ln = tid & 63;
  int wm = wid >> 2, wn = wid & 3;
  int lm = ln & 15, lq = ln >> 4;

  int rb = tid >> 2;
  int srcs = ((tid & 3) ^ ((tid >> 3) & 3)) * 16;
  const char* gA[2]; const char* gB[2];
#pragma unroll
  for (int r = 0; r < 2; r++) {
    int row = r0 + r * 128 + rb;  // may exceed Ne: reads slack rows, discarded
    gA[r] = (const char*)(hmid + (size_t)(base + row - chunk_base) * IDIM) + srcs;
    gB[r] = (const char*)(w2b + (size_t)g * HDIM * IDIM +
                          (size_t)(n0 + r * 128 + rb) * IDIM) + srcs;
  }
  int swz = (lq ^ ((lm >> 1) & 3)) * 16;
  int rdA = (wm * 128 + lm) * 64 + swz;
  int rdB = 16384 + (wn * 64 + lm) * 64 + swz;

  floatx4 acc[8][4] = {};

#define STAGE_A2(T) { int b_ = (T) & 3; size_t ko = (size_t)(T) * 64; \
    gload16(gA[0] + ko, smem + b_ * 32768 + tid * 16); \
    gload16(gA[1] + ko, smem + b_ * 32768 + 8192 + tid * 16); }
#define STAGE_B2(T) { int b_ = (T) & 3; size_t ko = (size_t)(T) * 64; \
    gload16(gB[0] + ko, smem + b_ * 32768 + 16384 + tid * 16); \
    gload16(gB[1] + ko, smem + b_ * 32768 + 24576 + tid * 16); }

  const int NT = IDIM / 32;
#pragma unroll
  for (int p = 0; p < 3; p++) { STAGE_A2(p); STAGE_B2(p); }

#pragma unroll 1
  for (int t = 0; t < NT; t++) {
    bool st = (t < NT - 3);
    if (st) STAGE_A2(t + 3);
    int rem = NT - 1 - t;
    if (rem >= 3)      asm volatile("s_waitcnt vmcnt(10)" ::: "memory");
    else if (rem == 2) asm volatile("s_waitcnt vmcnt(8)" ::: "memory");
    else if (rem == 1) asm volatile("s_waitcnt vmcnt(4)" ::: "memory");
    else               asm volatile("s_waitcnt vmcnt(0)" ::: "memory");
    __builtin_amdgcn_s_barrier();
    asm volatile("" ::: "memory");
    const char* cb = smem + (t & 3) * 32768;
    bf16x8 af[8], bf[2];
#pragma unroll
    for (int mi = 0; mi < 8; mi++) af[mi] = *(const bf16x8*)(cb + rdA + mi * 1024);
#pragma unroll
    for (int ni = 0; ni < 2; ni++) bf[ni] = *(const bf16x8*)(cb + rdB + ni * 1024);
    __builtin_amdgcn_s_setprio(1);
#pragma unroll
    for (int mi = 0; mi < 8; mi++)
#pragma unroll
      for (int ni = 0; ni < 2; ni++)
        acc[mi][ni] = __builtin_amdgcn_mfma_f32_16x16x32_bf16(af[mi], bf[ni], acc[mi][ni], 0, 0, 0);
    __builtin_amdgcn_s_setprio(0);
    if (st) STAGE_B2(t + 3);
    bf16x8 bg[2];
#pragma unroll
    for (int ni = 0; ni < 2; ni++) bg[ni] = *(const bf16x8*)(cb + rdB + (2 + ni) * 1024);
    __builtin_amdgcn_s_setprio(1);
#pragma unroll
    for (int mi = 0; mi < 8; mi++)
#pragma unroll
      for (int ni = 0; ni < 2; ni++)
        acc[mi][2 + ni] = __builtin_amdgcn_mfma_f32_16x16x32_bf16(af[mi], bg[ni], acc[mi][2 + ni], 0, 0, 0);
    __builtin_amdgcn_s_setprio(0);
    asm volatile("" ::: "memory");
    __builtin_amdgcn_s_barrier();
    asm volatile("" ::: "memory");
  }
#undef STAGE_A2
#undef STAGE_B2

  int colbase = n0 + wn * 64;
#pragma unroll
  for (int mi = 0; mi < 8; mi++) {
#pragma unroll
    for (int reg = 0; reg < 4; reg++) {
      int rr = r0 + wm * 128 + mi * 16 + lq * 4 + reg;
      if (rr < Ne) {
        int t = row_info[base + rr];
        float gate = row_gate[base + rr];
        float* orow = out + (size_t)t * HDIM;
#pragma unroll
        for (int ni = 0; ni < 4; ni++) {
          int c = colbase + ni * 16 + lm;
          float v = gate * (acc[mi][ni][reg] + b2[g * HDIM + c]);
          atomicAdd(&orow[c], v);
        }
      }
    }
  }
}

extern "C" void kernel_launch(void* const* d_in, const int* in_sizes, int n_in,
                              void* d_out, int out_size, void* d_ws, size_t ws_size,
                              hipStream_t stream) {
  (void)in_sizes; (void)n_in; (void)out_size;
  const float* x  = (const float*)d_in[0];
  const float* Wg = (const float*)d_in[1];
  const float* W1 = (const float*)d_in[2];
  const float* b1 = (const float*)d_in[3];
  const float* W2 = (const float*)d_in[4];
  const float* b2 = (const float*)d_in[5];
  float* out = (float*)d_out;
  float* logits = out + (size_t)T_TOK * HDIM;

  const size_t xb_b   = (size_t)T_TOK * HDIM * 2;
  const size_t w_b    = (size_t)NEXP * IDIM * HDIM * 2;
  const size_t side_b = (size_t)2 * T_TOK * 4;
  const size_t meta_b = 32768;
  // CH=2: hmid chunk ~134MB -> L3-resident between gemm1 and gemm2's passes.
  int CH = 2;
  while (CH < 16) {
    size_t hm = ((size_t)((2 * T_TOK) / CH) + 256) * IDIM * 2;
    size_t need = xb_b + 2 * w_b + hm + 4 * side_b + meta_b + 8192;
    if (need <= ws_size) break;
    CH *= 2;
  }
  const int R = (2 * T_TOK) / CH;

  char* p = (char*)d_ws;
  size_t off = 0;
  auto take = [&](size_t bytes) -> char* {
    char* r = p + off;
    off = (off + bytes + 255) & ~(size_t)255;
    return r;
  };
  __bf16* xb   = (__bf16*)take(xb_b);
  __bf16* w1b  = (__bf16*)take(w_b);
  __bf16* w2b  = (__bf16*)take(w_b);
  __bf16* hmid = (__bf16*)take(((size_t)R + 256) * IDIM * 2);
  int*   topk_e   = (int*)take(side_b);
  float* topk_g   = (float*)take(side_b);
  int*   row_info = (int*)take(side_b);
  float* row_gate = (float*)take(side_b);
  int*   gcount   = (int*)take(16 * 4);
  int*   goff     = (int*)take(17 * 4);
  int*   gcur     = (int*)take(16 * 4);
  int*   ntb      = (int*)take(16 * 4);
  int*   tbl      = (int*)take(16 * 288 * 4);

  hipMemsetAsync(gcount, 0, 16 * 4, stream);
  hipMemsetAsync(out, 0, (size_t)T_TOK * HDIM * 4, stream);

  cvtk<<<(T_TOK * HDIM / 8) / 256, 256, 0, stream>>>(x, xb, T_TOK * HDIM / 8);
  cvtk<<<(NEXP * IDIM * HDIM / 8) / 256, 256, 0, stream>>>(W1, w1b, NEXP * IDIM * HDIM / 8);
  cvtk<<<(NEXP * IDIM * HDIM / 8) / 256, 256, 0, stream>>>(W2, w2b, NEXP * IDIM * HDIM / 8);
  routerk<<<T_TOK / 64, 256, 0, stream>>>(x, Wg, logits, topk_e, topk_g, gcount);
  prefixk<<<1, 64, 0, stream>>>(gcount, goff, gcur, tbl, ntb, CH);
  scatterk<<<T_TOK / 256, 256, 0, stream>>>(topk_e, topk_g, gcur, row_info, row_gate);

  int gx = R / 256 + 8;
  for (int c = 0; c < CH; c++) {
    gemm1k<<<dim3(gx, IDIM / 256, 1), 512, 0, stream>>>(
        xb, w1b, b1, hmid, row_info, goff, tbl + c * 288, ntb + c, c * R);
    gemm2k<<<dim3(gx, HDIM / 256, 1), 512, 0, stream>>>(
        hmid, w2b, b2, out, row_info, row_gate, goff, tbl + c * 288, ntb + c, c * R);
  }
}

// Round 4
// 1449.172 us; speedup vs baseline: 1.0936x; 1.0936x over previous
//
#include <hip/hip_runtime.h>
#include <hip/hip_bf16.h>
#include <stdint.h>

#define T_TOK 16384
#define HDIM  1024
#define IDIM  4096
#define NEXP  8

typedef __bf16  bf16x8  __attribute__((ext_vector_type(8)));
typedef float   floatx4 __attribute__((ext_vector_type(4)));

__device__ __forceinline__ void gload16(const void* g, void* lds) {
  __builtin_amdgcn_global_load_lds(
      (__attribute__((address_space(1))) void*)g,
      (__attribute__((address_space(3))) void*)lds, 16, 0, 0);
}

// ---------------- fp32 -> bf16 convert, 8 elems/thread ----------------
__global__ __launch_bounds__(256) void cvtk(const float* __restrict__ s,
                                            __bf16* __restrict__ d, int n8) {
  int i = blockIdx.x * 256 + threadIdx.x;
  if (i >= n8) return;
  const float4* s4 = (const float4*)s;
  float4 a = s4[2 * i], b = s4[2 * i + 1];
  bf16x8 v;
  v[0] = (__bf16)a.x; v[1] = (__bf16)a.y; v[2] = (__bf16)a.z; v[3] = (__bf16)a.w;
  v[4] = (__bf16)b.x; v[5] = (__bf16)b.y; v[6] = (__bf16)b.z; v[7] = (__bf16)b.w;
  *(bf16x8*)(d + (size_t)i * 8) = v;
}

// ---------------- router: fp32 logits, top-2, per-block LDS histogram ----------------
__global__ __launch_bounds__(256) void routerk(const float* __restrict__ x,
    const float* __restrict__ Wg, float* __restrict__ logits,
    int* __restrict__ topk_e, float* __restrict__ topk_g,
    int* __restrict__ gcount) {
  __shared__ int hist[NEXP];
  int tid = threadIdx.x;
  if (tid < NEXP) hist[tid] = 0;
  __syncthreads();
  int wv = tid >> 6, ln = tid & 63;
  for (int it = 0; it < 16; ++it) {
    int t = blockIdx.x * 64 + wv * 16 + it;
    const float* xr = x + (size_t)t * HDIM;
    float acc[NEXP];
#pragma unroll
    for (int e = 0; e < NEXP; e++) acc[e] = 0.f;
    for (int h = ln; h < HDIM; h += 64) {
      float xv = xr[h];
#pragma unroll
      for (int e = 0; e < NEXP; e++) acc[e] += xv * Wg[e * HDIM + h];
    }
#pragma unroll
    for (int e = 0; e < NEXP; e++) {
#pragma unroll
      for (int off = 32; off > 0; off >>= 1) acc[e] += __shfl_down(acc[e], off);
    }
    if (ln == 0) {
#pragma unroll
      for (int e = 0; e < NEXP; e++) logits[(size_t)t * NEXP + e] = acc[e];
      int i0 = 0;
#pragma unroll
      for (int e = 1; e < NEXP; e++) if (acc[e] > acc[i0]) i0 = e;
      int i1 = (i0 == 0) ? 1 : 0;
#pragma unroll
      for (int e = 0; e < NEXP; e++)
        if (e != i0 && e != i1 && acc[e] > acc[i1]) i1 = e;
      float r = expf(acc[i1] - acc[i0]);
      float s = 1.f + r;
      topk_e[2 * t] = i0;     topk_g[2 * t] = 1.f / s;
      topk_e[2 * t + 1] = i1; topk_g[2 * t + 1] = r / s;
      atomicAdd(&hist[i0], 1);
      atomicAdd(&hist[i1], 1);
    }
  }
  __syncthreads();
  if (tid < NEXP) atomicAdd(&gcount[tid], hist[tid]);
}

// ---------------- prefix + block tables (256-row blocks) ----------------
__global__ void prefixk(const int* __restrict__ gcount, int* __restrict__ goff,
                        int* __restrict__ gcur, int* __restrict__ tbl,
                        int* __restrict__ ntb, int CH) {
  if (threadIdx.x != 0 || blockIdx.x != 0) return;
  int s = 0;
  for (int g = 0; g < NEXP; g++) { goff[g] = s; gcur[g] = s; s += gcount[g]; }
  goff[NEXP] = s;
  int chunk_rows = (2 * T_TOK) / CH;
  int cnt[16];
  for (int c = 0; c < CH; c++) cnt[c] = 0;
  for (int g = 0; g < NEXP; g++) {
    int Ne = goff[g + 1] - goff[g];
    int nb = (Ne + 255) >> 8;
    for (int b = 0; b < nb; b++) {
      int gr0 = goff[g] + b * 256;
      int c = gr0 / chunk_rows;
      tbl[c * 288 + cnt[c]] = (g << 8) | b;
      cnt[c]++;
    }
  }
  for (int c = 0; c < CH; c++) ntb[c] = cnt[c];
}

// ---------------- scatter: per-block LDS histogram + block-range reservation ----------------
__global__ __launch_bounds__(256) void scatterk(const int* __restrict__ topk_e,
    const float* __restrict__ topk_g, int* __restrict__ gcur,
    int* __restrict__ row_info, float* __restrict__ row_gate) {
  __shared__ int hist[NEXP];
  __shared__ int bbase[NEXP];
  int tid = threadIdx.x;
  if (tid < NEXP) hist[tid] = 0;
  __syncthreads();
  int t = blockIdx.x * 256 + tid;
  int e0 = topk_e[2 * t], e1 = topk_e[2 * t + 1];
  float g0 = topk_g[2 * t], g1 = topk_g[2 * t + 1];
  int l0 = atomicAdd(&hist[e0], 1);
  int l1 = atomicAdd(&hist[e1], 1);
  __syncthreads();
  if (tid < NEXP) bbase[tid] = atomicAdd(&gcur[tid], hist[tid]);
  __syncthreads();
  int p0 = bbase[e0] + l0;
  row_info[p0] = t; row_gate[p0] = g0;
  int p1 = bbase[e1] + l1;
  row_info[p1] = t; row_gate[p1] = g1;
}

// ============================================================================
// GEMM core: 256x256 tile, 8 waves (2M x 4N), BK=32, 16x16x32 bf16 MFMA.
//  - 4 LDS buffers x 32KB, prefetch distance 3 tiles, counted vmcnt (never 0
//    in steady state). Verified: SQ_LDS_BANK_CONFLICT == 0 (swizzle works).
//  - CH=1 (round 4): the kernel is 1 block/CU (128KB LDS); per chunk the
//    gemm2 grid was 280 blocks -> 2 rounds, 2nd round 24/256 CUs = 45% of
//    the dispatch wasted. One dispatch of ~540 blocks packs at 3 rounds
//    (~93%). hmid leaves L3 residency, but required BW ~2.5 TB/s << 6.3
//    and the depth-3 pipeline (~4000cy cover) hides HBM latency by design.
// ============================================================================

// ---------------- GEMM1: hmid = silu(x @ W1[e]^T + b1[e]), bf16 out ----------------
__global__ __launch_bounds__(512, 2) void gemm1k(
    const __bf16* __restrict__ xb, const __bf16* __restrict__ w1b,
    const float* __restrict__ b1, __bf16* __restrict__ hmid,
    const int* __restrict__ row_info, const int* __restrict__ goff,
    const int* __restrict__ tbl, const int* __restrict__ ntb, int chunk_base) {
  __shared__ __attribute__((aligned(16))) char smem[131072];
  if ((int)blockIdx.x >= ntb[0]) return;
  int info = tbl[blockIdx.x];
  int g = info >> 8, br = info & 255;
  int base = goff[g];
  int Ne = goff[g + 1] - base;
  int r0 = br * 256;
  if (r0 >= Ne) return;
  int n0 = blockIdx.y * 256;
  int tid = threadIdx.x, wid = tid >> 6, ln = tid & 63;
  int wm = wid >> 2, wn = wid & 3;
  int lm = ln & 15, lq = ln >> 4;

  int rb = tid >> 2;
  int srcs = ((tid & 3) ^ ((tid >> 3) & 3)) * 16;
  const char* gA[2]; const char* gB[2];
#pragma unroll
  for (int r = 0; r < 2; r++) {
    int row = r0 + r * 128 + rb;
    int rc = row < Ne ? row : Ne - 1;
    int tk = row_info[base + rc];
    gA[r] = (const char*)(xb + (size_t)tk * HDIM) + srcs;
    gB[r] = (const char*)(w1b + (size_t)g * IDIM * HDIM +
                          (size_t)(n0 + r * 128 + rb) * HDIM) + srcs;
  }
  int swz = (lq ^ ((lm >> 1) & 3)) * 16;
  int rdA = (wm * 128 + lm) * 64 + swz;
  int rdB = 16384 + (wn * 64 + lm) * 64 + swz;

  floatx4 acc[8][4] = {};

#define STAGE_A1(T) { int b_ = (T) & 3; size_t ko = (size_t)(T) * 64; \
    gload16(gA[0] + ko, smem + b_ * 32768 + tid * 16); \
    gload16(gA[1] + ko, smem + b_ * 32768 + 8192 + tid * 16); }
#define STAGE_B1(T) { int b_ = (T) & 3; size_t ko = (size_t)(T) * 64; \
    gload16(gB[0] + ko, smem + b_ * 32768 + 16384 + tid * 16); \
    gload16(gB[1] + ko, smem + b_ * 32768 + 24576 + tid * 16); }

  const int NT = HDIM / 32;
#pragma unroll
  for (int p = 0; p < 3; p++) { STAGE_A1(p); STAGE_B1(p); }

#pragma unroll 1
  for (int t = 0; t < NT; t++) {
    bool st = (t < NT - 3);
    if (st) STAGE_A1(t + 3);
    int rem = NT - 1 - t;
    if (rem >= 3)      asm volatile("s_waitcnt vmcnt(10)" ::: "memory");
    else if (rem == 2) asm volatile("s_waitcnt vmcnt(8)" ::: "memory");
    else if (rem == 1) asm volatile("s_waitcnt vmcnt(4)" ::: "memory");
    else               asm volatile("s_waitcnt vmcnt(0)" ::: "memory");
    __builtin_amdgcn_s_barrier();
    asm volatile("" ::: "memory");
    const char* cb = smem + (t & 3) * 32768;
    bf16x8 af[8], bf[2];
#pragma unroll
    for (int mi = 0; mi < 8; mi++) af[mi] = *(const bf16x8*)(cb + rdA + mi * 1024);
#pragma unroll
    for (int ni = 0; ni < 2; ni++) bf[ni] = *(const bf16x8*)(cb + rdB + ni * 1024);
    __builtin_amdgcn_s_setprio(1);
#pragma unroll
    for (int mi = 0; mi < 8; mi++)
#pragma unroll
      for (int ni = 0; ni < 2; ni++)
        acc[mi][ni] = __builtin_amdgcn_mfma_f32_16x16x32_bf16(af[mi], bf[ni], acc[mi][ni], 0, 0, 0);
    __builtin_amdgcn_s_setprio(0);
    if (st) STAGE_B1(t + 3);
    bf16x8 bg[2];
#pragma unroll
    for (int ni = 0; ni < 2; ni++) bg[ni] = *(const bf16x8*)(cb + rdB + (2 + ni) * 1024);
    __builtin_amdgcn_s_setprio(1);
#pragma unroll
    for (int mi = 0; mi < 8; mi++)
#pragma unroll
      for (int ni = 0; ni < 2; ni++)
        acc[mi][2 + ni] = __builtin_amdgcn_mfma_f32_16x16x32_bf16(af[mi], bg[ni], acc[mi][2 + ni], 0, 0, 0);
    __builtin_amdgcn_s_setprio(0);
    asm volatile("" ::: "memory");
    __builtin_amdgcn_s_barrier();
    asm volatile("" ::: "memory");
  }
#undef STAGE_A1
#undef STAGE_B1

  int colbase = n0 + wn * 64;
#pragma unroll
  for (int mi = 0; mi < 8; mi++) {
#pragma unroll
    for (int reg = 0; reg < 4; reg++) {
      int rr = r0 + wm * 128 + mi * 16 + lq * 4 + reg;
      if (rr < Ne) {
        __bf16* orow = hmid + (size_t)(base + rr - chunk_base) * IDIM;
#pragma unroll
        for (int ni = 0; ni < 4; ni++) {
          int c = colbase + ni * 16 + lm;
          float v = acc[mi][ni][reg] + b1[g * IDIM + c];
          v = v / (1.f + __expf(-v));
          orow[c] = (__bf16)v;
        }
      }
    }
  }
}

// ---------------- GEMM2: out += gate * (hmid @ W2[e]^T + b2[e]) ----------------
__global__ __launch_bounds__(512, 2) void gemm2k(
    const __bf16* __restrict__ hmid, const __bf16* __restrict__ w2b,
    const float* __restrict__ b2, float* __restrict__ out,
    const int* __restrict__ row_info, const float* __restrict__ row_gate,
    const int* __restrict__ goff, const int* __restrict__ tbl,
    const int* __restrict__ ntb, int chunk_base) {
  __shared__ __attribute__((aligned(16))) char smem[131072];
  if ((int)blockIdx.x >= ntb[0]) return;
  int info = tbl[blockIdx.x];
  int g = info >> 8, br = info & 255;
  int base = goff[g];
  int Ne = goff[g + 1] - base;
  int r0 = br * 256;
  if (r0 >= Ne) return;
  int n0 = blockIdx.y * 256;
  int tid = threadIdx.x, wid = tid >> 6, ln = tid & 63;
  int wm = wid >> 2, wn = wid & 3;
  int lm = ln & 15, lq = ln >> 4;

  int rb = tid >> 2;
  int srcs = ((tid & 3) ^ ((tid >> 3) & 3)) * 16;
  const char* gA[2]; const char* gB[2];
#pragma unroll
  for (int r = 0; r < 2; r++) {
    int row = r0 + r * 128 + rb;  // may exceed Ne: reads slack rows, discarded
    gA[r] = (const char*)(hmid + (size_t)(base + row - chunk_base) * IDIM) + srcs;
    gB[r] = (const char*)(w2b + (size_t)g * HDIM * IDIM +
                          (size_t)(n0 + r * 128 + rb) * IDIM) + srcs;
  }
  int swz = (lq ^ ((lm >> 1) & 3)) * 16;
  int rdA = (wm * 128 + lm) * 64 + swz;
  int rdB = 16384 + (wn * 64 + lm) * 64 + swz;

  floatx4 acc[8][4] = {};

#define STAGE_A2(T) { int b_ = (T) & 3; size_t ko = (size_t)(T) * 64; \
    gload16(gA[0] + ko, smem + b_ * 32768 + tid * 16); \
    gload16(gA[1] + ko, smem + b_ * 32768 + 8192 + tid * 16); }
#define STAGE_B2(T) { int b_ = (T) & 3; size_t ko = (size_t)(T) * 64; \
    gload16(gB[0] + ko, smem + b_ * 32768 + 16384 + tid * 16); \
    gload16(gB[1] + ko, smem + b_ * 32768 + 24576 + tid * 16); }

  const int NT = IDIM / 32;
#pragma unroll
  for (int p = 0; p < 3; p++) { STAGE_A2(p); STAGE_B2(p); }

#pragma unroll 1
  for (int t = 0; t < NT; t++) {
    bool st = (t < NT - 3);
    if (st) STAGE_A2(t + 3);
    int rem = NT - 1 - t;
    if (rem >= 3)      asm volatile("s_waitcnt vmcnt(10)" ::: "memory");
    else if (rem == 2) asm volatile("s_waitcnt vmcnt(8)" ::: "memory");
    else if (rem == 1) asm volatile("s_waitcnt vmcnt(4)" ::: "memory");
    else               asm volatile("s_waitcnt vmcnt(0)" ::: "memory");
    __builtin_amdgcn_s_barrier();
    asm volatile("" ::: "memory");
    const char* cb = smem + (t & 3) * 32768;
    bf16x8 af[8], bf[2];
#pragma unroll
    for (int mi = 0; mi < 8; mi++) af[mi] = *(const bf16x8*)(cb + rdA + mi * 1024);
#pragma unroll
    for (int ni = 0; ni < 2; ni++) bf[ni] = *(const bf16x8*)(cb + rdB + ni * 1024);
    __builtin_amdgcn_s_setprio(1);
#pragma unroll
    for (int mi = 0; mi < 8; mi++)
#pragma unroll
      for (int ni = 0; ni < 2; ni++)
        acc[mi][ni] = __builtin_amdgcn_mfma_f32_16x16x32_bf16(af[mi], bf[ni], acc[mi][ni], 0, 0, 0);
    __builtin_amdgcn_s_setprio(0);
    if (st) STAGE_B2(t + 3);
    bf16x8 bg[2];
#pragma unroll
    for (int ni = 0; ni < 2; ni++) bg[ni] = *(const bf16x8*)(cb + rdB + (2 + ni) * 1024);
    __builtin_amdgcn_s_setprio(1);
#pragma unroll
    for (int mi = 0; mi < 8; mi++)
#pragma unroll
      for (int ni = 0; ni < 2; ni++)
        acc[mi][2 + ni] = __builtin_amdgcn_mfma_f32_16x16x32_bf16(af[mi], bg[ni], acc[mi][2 + ni], 0, 0, 0);
    __builtin_amdgcn_s_setprio(0);
    asm volatile("" ::: "memory");
    __builtin_amdgcn_s_barrier();
    asm volatile("" ::: "memory");
  }
#undef STAGE_A2
#undef STAGE_B2

  int colbase = n0 + wn * 64;
#pragma unroll
  for (int mi = 0; mi < 8; mi++) {
#pragma unroll
    for (int reg = 0; reg < 4; reg++) {
      int rr = r0 + wm * 128 + mi * 16 + lq * 4 + reg;
      if (rr < Ne) {
        int t = row_info[base + rr];
        float gate = row_gate[base + rr];
        float* orow = out + (size_t)t * HDIM;
#pragma unroll
        for (int ni = 0; ni < 4; ni++) {
          int c = colbase + ni * 16 + lm;
          float v = gate * (acc[mi][ni][reg] + b2[g * HDIM + c]);
          atomicAdd(&orow[c], v);
        }
      }
    }
  }
}

extern "C" void kernel_launch(void* const* d_in, const int* in_sizes, int n_in,
                              void* d_out, int out_size, void* d_ws, size_t ws_size,
                              hipStream_t stream) {
  (void)in_sizes; (void)n_in; (void)out_size;
  const float* x  = (const float*)d_in[0];
  const float* Wg = (const float*)d_in[1];
  const float* W1 = (const float*)d_in[2];
  const float* b1 = (const float*)d_in[3];
  const float* W2 = (const float*)d_in[4];
  const float* b2 = (const float*)d_in[5];
  float* out = (float*)d_out;
  float* logits = out + (size_t)T_TOK * HDIM;

  const size_t xb_b   = (size_t)T_TOK * HDIM * 2;
  const size_t w_b    = (size_t)NEXP * IDIM * HDIM * 2;
  const size_t side_b = (size_t)2 * T_TOK * 4;
  const size_t meta_b = 32768;
  // CH=1: single dispatch per GEMM. 1-block/CU kernel => packing dominates:
  // gemm2 at CH=2 was 280 blocks = 2 rounds (2nd at 9% util); CH=1 is 540
  // blocks = 3 rounds at ~93% packing. hmid streams from HBM (~2.5 TB/s
  // demand, covered by the depth-3 prefetch pipeline).
  int CH = 1;
  while (CH < 16) {
    size_t hm = ((size_t)((2 * T_TOK) / CH) + 256) * IDIM * 2;
    size_t need = xb_b + 2 * w_b + hm + 4 * side_b + meta_b + 8192;
    if (need <= ws_size) break;
    CH *= 2;
  }
  const int R = (2 * T_TOK) / CH;

  char* p = (char*)d_ws;
  size_t off = 0;
  auto take = [&](size_t bytes) -> char* {
    char* r = p + off;
    off = (off + bytes + 255) & ~(size_t)255;
    return r;
  };
  __bf16* xb   = (__bf16*)take(xb_b);
  __bf16* w1b  = (__bf16*)take(w_b);
  __bf16* w2b  = (__bf16*)take(w_b);
  __bf16* hmid = (__bf16*)take(((size_t)R + 256) * IDIM * 2);
  int*   topk_e   = (int*)take(side_b);
  float* topk_g   = (float*)take(side_b);
  int*   row_info = (int*)take(side_b);
  float* row_gate = (float*)take(side_b);
  int*   gcount   = (int*)take(16 * 4);
  int*   goff     = (int*)take(17 * 4);
  int*   gcur     = (int*)take(16 * 4);
  int*   ntb      = (int*)take(16 * 4);
  int*   tbl      = (int*)take(16 * 288 * 4);

  hipMemsetAsync(gcount, 0, 16 * 4, stream);
  hipMemsetAsync(out, 0, (size_t)T_TOK * HDIM * 4, stream);

  cvtk<<<(T_TOK * HDIM / 8) / 256, 256, 0, stream>>>(x, xb, T_TOK * HDIM / 8);
  cvtk<<<(NEXP * IDIM * HDIM / 8) / 256, 256, 0, stream>>>(W1, w1b, NEXP * IDIM * HDIM / 8);
  cvtk<<<(NEXP * IDIM * HDIM / 8) / 256, 256, 0, stream>>>(W2, w2b, NEXP * IDIM * HDIM / 8);
  routerk<<<T_TOK / 64, 256, 0, stream>>>(x, Wg, logits, topk_e, topk_g, gcount);
  prefixk<<<1, 64, 0, stream>>>(gcount, goff, gcur, tbl, ntb, CH);
  scatterk<<<T_TOK / 256, 256, 0, stream>>>(topk_e, topk_g, gcur, row_info, row_gate);

  int gx = R / 256 + 8;
  for (int c = 0; c < CH; c++) {
    gemm1k<<<dim3(gx, IDIM / 256, 1), 512, 0, stream>>>(
        xb, w1b, b1, hmid, row_info, goff, tbl + c * 288, ntb + c, c * R);
    gemm2k<<<dim3(gx, HDIM / 256, 1), 512, 0, stream>>>(
        hmid, w2b, b2, out, row_info, row_gate, goff, tbl + c * 288, ntb + c, c * R);
  }
}